// Round 7
// baseline (2557.766 us; speedup 1.0000x reference)
//
#include <hip/hip_runtime.h>
#include <math.h>

// Problem constants
#define B_SZ   1024
#define H_SZ   512
#define E_SZ   100
#define L_SZ   128
#define KX     128          // embedding width padded 100 -> 128
#define VOCAB  50000
#define KW     648          // LDS weight row stride (fp16): 640 + 8 pad
                            // 324-word stride -> 2-way bank aliasing max (free)

typedef _Float16 f16x8 __attribute__((ext_vector_type(8)));
typedef float    f32x4 __attribute__((ext_vector_type(4)));

#define MFMA16(a, b, c) __builtin_amdgcn_mfma_f32_16x16x32_f16((a), (b), (c), 0, 0, 0)

__device__ __forceinline__ float fast_sigmoid(float x) {
    return __builtin_amdgcn_rcpf(1.0f + __expf(-x));
}
__device__ __forceinline__ float fast_tanh(float x) {
    return 1.0f - 2.0f * __builtin_amdgcn_rcpf(1.0f + __expf(2.0f * x));
}

// ---- device-scope (sc1 / LLC-coherent) h-state accessors ----
// Relaxed agent-scope atomics: loads read through to the Infinity Cache
// (bypassing possibly-stale per-XCD L2), stores write through to it.
// No acquire/release cache maintenance needed anywhere in the loop.
// CRITICAL (R7): relaxed atomic loads carry no waitcnt of their own, but the
// scheduler will NOT hoist them past other ops -- so they must be issued
// back-to-back in SOURCE order to pipeline. See the half-pass structure.
__device__ __forceinline__ f16x8 load_h16(const _Float16* p) {
    unsigned long long lo = __hip_atomic_load((unsigned long long*)p,
                                              __ATOMIC_RELAXED, __HIP_MEMORY_SCOPE_AGENT);
    unsigned long long hi = __hip_atomic_load((unsigned long long*)p + 1,
                                              __ATOMIC_RELAXED, __HIP_MEMORY_SCOPE_AGENT);
    union { unsigned long long q[2]; f16x8 v; } u;
    u.q[0] = lo; u.q[1] = hi;
    return u.v;
}
__device__ __forceinline__ void store_h1(_Float16* p, float v) {
    union { unsigned short s; _Float16 h; } u; u.h = (_Float16)v;
    __hip_atomic_store((unsigned short*)p, u.s,
                       __ATOMIC_RELAXED, __HIP_MEMORY_SCOPE_AGENT);
}

// ---------------------------------------------------------------------------
// Convert embedding tables to fp16, pad rows 100 -> 128.
// ---------------------------------------------------------------------------
__global__ __launch_bounds__(256) void prep_emb_kernel(
    _Float16* __restrict__ ef_c, const float* __restrict__ e_c,
    _Float16* __restrict__ ef_r, const float* __restrict__ e_r)
{
    const int PER = VOCAB * KX;                // 6,400,000
    int idx = blockIdx.x * 256 + threadIdx.x;
    if (idx >= 2 * PER) return;
    const int gru = idx >= PER;
    const int local = gru ? idx - PER : idx;
    const int v = local >> 7;                  // /128
    const int e = local & 127;
    const float* src = gru ? e_r : e_c;
    _Float16* dst = gru ? ef_r : ef_c;
    dst[local] = (_Float16)(e < E_SZ ? src[v * E_SZ + e] : 0.0f);
}

// ---------------------------------------------------------------------------
// Persistent GRU kernel: all 128 time steps in ONE launch.
// 256 blocks x 512 threads = 2 GRUs x 8 m-tiles(128 rows) x 16 u-slices(32u).
// LDS 124,416 B -> 1 block/CU; weights staged to LDS once.
//
// R7 changes vs R6 (theory: sc1 atomic loads were SERIALIZED ~900cyc each
// because the scheduler can't hoist atomics past MFMAs -> ~15us/step):
//  (1) A-frag loads batch-issued: two half-passes, each = 16 contiguous
//      atomic loads into register arrays, THEN 48 MFMAs. One latency
//      exposure per batch instead of ~16.
//  (2) h_prev for the z-blend carried in REGISTERS across steps (this
//      thread stored exactly that value last step) -- hp loads deleted.
//      Rounded through fp16 so it bit-matches what other blocks read.
//  (3) publish stays RELAXED (no buffer_wbl2) -- R6's win.
// ---------------------------------------------------------------------------
struct GruArgs {
    const float* Whh[2];
    const float* Wih[2];
    const float* bih[2];
    const float* bhh[2];
    const _Float16* emb[2];
    const int* idx[2];
    _Float16* hA;          // [2][1024][512] ping (h0 = 0, final h)
    _Float16* hB;          // [2][1024][512] pong
    unsigned int* bars;    // 16 groups, stride 32 uints (128B apart)
};

__global__ __launch_bounds__(512, 2) void gru_persistent(GruArgs args)
{
    const int blk = blockIdx.x;
    const int gru = blk >> 7;
    const int mt  = (blk >> 4) & 7;
    const int ut  = blk & 15;
    const int grp = (gru << 3) | mt;

    const float* __restrict__ Whh = args.Whh[gru];
    const float* __restrict__ Wih = args.Wih[gru];
    const float* __restrict__ bih = args.bih[gru];
    const float* __restrict__ bhh = args.bhh[gru];
    const _Float16* __restrict__ embf = args.emb[gru];
    const int* __restrict__ idx = args.idx[gru];

    const int u0 = ut * 32;        // block's hidden-unit base (32 units)
    const int mB = mt * 128;       // block's batch-row base (128 rows)

    __shared__ _Float16 Wl[3][32][KW];   // 124,416 B

    // ---- stage weights fp32 -> fp16 into LDS (once) ----
    for (int r = 0; r < 96; ++r) {            // r = gate*32 + uu
        const int g = r >> 5, uu = r & 31;
        const int row = g * H_SZ + u0 + uu;
        for (int k = threadIdx.x; k < KW; k += 512) {
            float v = 0.0f;
            if (k < H_SZ)                 v = Whh[row * H_SZ + k];
            else if (k < H_SZ + E_SZ)     v = Wih[row * E_SZ + (k - H_SZ)];
            Wl[g][uu][k] = (_Float16)v;
        }
    }
    __syncthreads();

    const int lane = threadIdx.x & 63;
    const int wave = threadIdx.x >> 6;   // 0..7
    const int lr   = lane & 15;          // fragment row
    const int kseg = lane >> 4;          // 0..3
    const int mw   = mB + (wave >> 1) * 32;  // wave's 32-row batch base
    const int uw   = (wave & 1) * 16;        // wave's 16-u half of block slice

    // bias preload (wave covers 16 fixed u's)
    const int ucol = u0 + uw + lr;
    const float bir  = bih[ucol]             + bhh[ucol];
    const float biz  = bih[H_SZ + ucol]      + bhh[H_SZ + ucol];
    const float binn = bih[2 * H_SZ + ucol];
    const float bhn  = bhh[2 * H_SZ + ucol];

    _Float16* hbuf0 = args.hA + (size_t)gru * B_SZ * H_SZ;
    _Float16* hbuf1 = args.hB + (size_t)gru * B_SZ * H_SZ;
    unsigned int* bar = args.bars + grp * 32;

    // h_prev at this thread's own output coordinates, carried in registers.
    // (h0 = 0, matching the memset'd hA this block's A-frags read at step 0.)
    float hreg[2][4] = {{0.f,0.f,0.f,0.f},{0.f,0.f,0.f,0.f}};

#pragma unroll 1
    for (int step = 0; step < L_SZ; ++step) {
        const _Float16* __restrict__ hin = (step & 1) ? hbuf1 : hbuf0;
        _Float16* __restrict__ hout      = (step & 1) ? hbuf0 : hbuf1;
        const int lcol = L_SZ - 1 - step;

        f32x4 accr[2], accz[2], acchn[2], accin[2];
#pragma unroll
        for (int i = 0; i < 2; i++) {
            accr[i]  = (f32x4){0.f, 0.f, 0.f, 0.f};
            accz[i]  = (f32x4){0.f, 0.f, 0.f, 0.f};
            acchn[i] = (f32x4){0.f, 0.f, 0.f, 0.f};
            accin[i] = (f32x4){0.f, 0.f, 0.f, 0.f};
        }

        // ---- x-part first (emb only -- independent of h(step)) ----
        const int iv0 = idx[(mw + lr) * L_SZ + lcol];
        const int iv1 = idx[(mw + 16 + lr) * L_SZ + lcol];
#pragma unroll
        for (int xc = 0; xc < 4; ++xc) {
            const int e0 = xc * 32 + kseg * 8;
            f16x8 a0 = *(const f16x8*)(embf + (size_t)iv0 * KX + e0);
            f16x8 a1 = *(const f16x8*)(embf + (size_t)iv1 * KX + e0);
            f16x8 b0 = *(const f16x8*)&Wl[0][uw + lr][H_SZ + e0];
            f16x8 b1 = *(const f16x8*)&Wl[1][uw + lr][H_SZ + e0];
            f16x8 b2 = *(const f16x8*)&Wl[2][uw + lr][H_SZ + e0];
            accr[0]  = MFMA16(a0, b0, accr[0]);
            accr[1]  = MFMA16(a1, b0, accr[1]);
            accz[0]  = MFMA16(a0, b1, accz[0]);
            accz[1]  = MFMA16(a1, b1, accz[1]);
            accin[0] = MFMA16(a0, b2, accin[0]);
            accin[1] = MFMA16(a1, b2, accin[1]);
        }

        // ---- wait for h(step) (group = 16 blocks sharing this m-tile) ----
        if (step > 0) {
            if (threadIdx.x == 0) {
                const unsigned tgt = 16u * (unsigned)step;
                while (__hip_atomic_load(bar, __ATOMIC_RELAXED,
                                         __HIP_MEMORY_SCOPE_AGENT) < tgt)
                    __builtin_amdgcn_s_sleep(1);
            }
            __syncthreads();
        }

        // ---- h-part: K = 512 in two half-passes.
        // Each half: 16 back-to-back sc1 loads (all in flight together),
        // then 48 MFMAs consuming them. ----
        const _Float16* hrow0 = hin + (mw + lr) * H_SZ + kseg * 8;
        const _Float16* hrow1 = hin + (mw + 16 + lr) * H_SZ + kseg * 8;
#pragma unroll
        for (int half = 0; half < 2; ++half) {
            const int kbase = half * 256;
            f16x8 a0[8], a1[8];
#pragma unroll
            for (int kc = 0; kc < 8; ++kc)
                a0[kc] = load_h16(hrow0 + kbase + kc * 32);
#pragma unroll
            for (int kc = 0; kc < 8; ++kc)
                a1[kc] = load_h16(hrow1 + kbase + kc * 32);
#pragma unroll
            for (int kc = 0; kc < 8; ++kc) {
                const int k0 = kbase + kc * 32 + kseg * 8;
                f16x8 b0 = *(const f16x8*)&Wl[0][uw + lr][k0];
                f16x8 b1 = *(const f16x8*)&Wl[1][uw + lr][k0];
                f16x8 b2 = *(const f16x8*)&Wl[2][uw + lr][k0];
                accr[0]  = MFMA16(a0[kc], b0, accr[0]);
                accr[1]  = MFMA16(a1[kc], b0, accr[1]);
                accz[0]  = MFMA16(a0[kc], b1, accz[0]);
                accz[1]  = MFMA16(a1[kc], b1, accz[1]);
                acchn[0] = MFMA16(a0[kc], b2, acchn[0]);
                acchn[1] = MFMA16(a1[kc], b2, acchn[1]);
            }
        }

        // ---- epilogue: gates + state update (sc1 write-through stores) ----
        // C/D layout: col = lane&15 (u), row = (lane>>4)*4 + reg (m)
#pragma unroll
        for (int mt2 = 0; mt2 < 2; ++mt2) {
#pragma unroll
            for (int r = 0; r < 4; ++r) {
                const int m = mw + mt2 * 16 + kseg * 4 + r;
                const float rg = fast_sigmoid(accr[mt2][r] + bir);
                const float zg = fast_sigmoid(accz[mt2][r] + biz);
                const float ng = fast_tanh(accin[mt2][r] + binn +
                                           rg * (acchn[mt2][r] + bhn));
                float nh = (1.0f - zg) * ng + zg * hreg[mt2][r];
                nh = (float)(_Float16)nh;       // bit-match the stored fp16
                hreg[mt2][r] = nh;
                store_h1(hout + m * H_SZ + ucol, nh);
            }
        }

        // ---- publish (RELAXED: no buffer_wbl2) ----
        if (step + 1 < L_SZ) {
            __syncthreads();   // emits s_waitcnt vmcnt(0): all sc1 stores acked
            if (threadIdx.x == 0) {
                __hip_atomic_fetch_add(bar, 1u, __ATOMIC_RELAXED,
                                       __HIP_MEMORY_SCOPE_AGENT);
            }
        }
    }
    // final h (step 127, odd) landed in hA via sc1 stores; the end-of-kernel
    // system-scope release makes it visible to the scores kernel.
}

// ---------------------------------------------------------------------------
// scores = hc @ hr^T (fp16 in, fp32 out), MFMA. Block 64x64, wave 32x32.
// ---------------------------------------------------------------------------
__global__ __launch_bounds__(256, 1) void scores_kernel(
    const _Float16* __restrict__ hc, const _Float16* __restrict__ hr,
    float* __restrict__ out)
{
    const int lane = threadIdx.x & 63;
    const int wave = threadIdx.x >> 6;
    const int lr   = lane & 15;
    const int kseg = lane >> 4;
    const int m0 = blockIdx.y * 64 + (wave >> 1) * 32;
    const int n0 = blockIdx.x * 64 + (wave & 1) * 32;

    f32x4 acc[2][2];
#pragma unroll
    for (int i = 0; i < 2; i++)
#pragma unroll
        for (int j = 0; j < 2; j++)
            acc[i][j] = (f32x4){0.f, 0.f, 0.f, 0.f};

#pragma unroll 2
    for (int kc = 0; kc < 16; kc++) {
        const int k0 = kc * 32 + kseg * 8;
        f16x8 a[2], b[2];
#pragma unroll
        for (int mt = 0; mt < 2; mt++)
            a[mt] = *(const f16x8*)(hc + (m0 + mt * 16 + lr) * H_SZ + k0);
#pragma unroll
        for (int nt = 0; nt < 2; nt++)
            b[nt] = *(const f16x8*)(hr + (n0 + nt * 16 + lr) * H_SZ + k0);
#pragma unroll
        for (int mt = 0; mt < 2; mt++)
#pragma unroll
            for (int nt = 0; nt < 2; nt++)
                acc[mt][nt] = MFMA16(a[mt], b[nt], acc[mt][nt]);
    }

#pragma unroll
    for (int mt = 0; mt < 2; mt++)
#pragma unroll
        for (int nt = 0; nt < 2; nt++)
#pragma unroll
            for (int r = 0; r < 4; r++) {
                const int m = m0 + mt * 16 + kseg * 4 + r;
                const int n = n0 + nt * 16 + lr;
                out[m * B_SZ + n] = acc[mt][nt][r];
            }
}

// In-place row softmax on [1024, 1024]; one block per row.
__global__ __launch_bounds__(256) void softmax_kernel(float* __restrict__ out)
{
    const int row = blockIdx.x;
    float* p = out + (size_t)row * B_SZ;
    const int t = threadIdx.x;
    const int wave = t >> 6;
    const int lane = t & 63;

    float4 v = ((const float4*)p)[t];
    float m = fmaxf(fmaxf(v.x, v.y), fmaxf(v.z, v.w));
#pragma unroll
    for (int off = 32; off >= 1; off >>= 1)
        m = fmaxf(m, __shfl_xor(m, off, 64));

    __shared__ float redm[4];
    if (lane == 0) redm[wave] = m;
    __syncthreads();
    m = fmaxf(fmaxf(redm[0], redm[1]), fmaxf(redm[2], redm[3]));

    const float e0 = __expf(v.x - m);
    const float e1 = __expf(v.y - m);
    const float e2 = __expf(v.z - m);
    const float e3 = __expf(v.w - m);
    float s = e0 + e1 + e2 + e3;
#pragma unroll
    for (int off = 32; off >= 1; off >>= 1)
        s += __shfl_xor(s, off, 64);

    __shared__ float reds[4];
    if (lane == 0) reds[wave] = s;
    __syncthreads();
    s = reds[0] + reds[1] + reds[2] + reds[3];

    const float inv = 1.0f / s;
    float4 o;
    o.x = e0 * inv; o.y = e1 * inv; o.z = e2 * inv; o.w = e3 * inv;
    ((float4*)p)[t] = o;
}

extern "C" void kernel_launch(void* const* d_in, const int* in_sizes, int n_in,
                              void* d_out, int out_size, void* d_ws, size_t ws_size,
                              hipStream_t stream)
{
    (void)in_sizes; (void)n_in; (void)out_size; (void)ws_size;

    const int*   contexts = (const int*)d_in[0];
    const int*   replies  = (const int*)d_in[1];
    const float* ctx_emb  = (const float*)d_in[2];
    const float* ctx_Wih  = (const float*)d_in[3];
    const float* ctx_Whh  = (const float*)d_in[4];
    const float* ctx_bih  = (const float*)d_in[5];
    const float* ctx_bhh  = (const float*)d_in[6];
    const float* rep_emb  = (const float*)d_in[7];
    const float* rep_Wih  = (const float*)d_in[8];
    const float* rep_Whh  = (const float*)d_in[9];
    const float* rep_bih  = (const float*)d_in[10];
    const float* rep_bhh  = (const float*)d_in[11];
    float* out = (float*)d_out;

    // ---- workspace layout (fp16 elements) ----
    const size_t EMB_ELEMS = (size_t)VOCAB * KX;          // 6,400,000
    const size_t H_ELEMS   = (size_t)B_SZ * H_SZ;         // 524,288

    _Float16* base   = (_Float16*)d_ws;
    _Float16* embf_c = base;
    _Float16* embf_r = embf_c + EMB_ELEMS;
    _Float16* hB     = embf_r + EMB_ELEMS;     // pong [2][B][H]
    _Float16* hA     = hB + 2 * H_ELEMS;       // ping [2][B][H]
    unsigned int* bars = (unsigned int*)(hA + 2 * H_ELEMS);  // 16*32 uints

    // zero h0 (both GRUs, ping buffer) AND the barrier counters in one shot.
    hipMemsetAsync(hA, 0, 2 * H_ELEMS * sizeof(_Float16) + 16 * 32 * sizeof(unsigned int), stream);

    // embedding tables fp32 -> fp16 (padded to 128)
    {
        const int total_emb = 2 * (int)EMB_ELEMS;
        prep_emb_kernel<<<(total_emb + 255) / 256, 256, 0, stream>>>(
            embf_c, ctx_emb, embf_r, rep_emb);
    }

    // one persistent kernel for all 128 GRU steps (both GRUs)
    GruArgs a;
    a.Whh[0] = ctx_Whh; a.Whh[1] = rep_Whh;
    a.Wih[0] = ctx_Wih; a.Wih[1] = rep_Wih;
    a.bih[0] = ctx_bih; a.bih[1] = rep_bih;
    a.bhh[0] = ctx_bhh; a.bhh[1] = rep_bhh;
    a.emb[0] = embf_c;  a.emb[1] = embf_r;
    a.idx[0] = contexts; a.idx[1] = replies;
    a.hA = hA; a.hB = hB; a.bars = bars;
    gru_persistent<<<dim3(256), dim3(512), 0, stream>>>(a);

    // final states: gru0 (ctx) at hA, gru1 (rep) at hA + B*H
    scores_kernel<<<dim3(B_SZ / 64, B_SZ / 64), 256, 0, stream>>>(hA, hA + H_ELEMS, out);
    softmax_kernel<<<B_SZ, 256, 0, stream>>>(out);
}

// Round 8
// 1722.611 us; speedup vs baseline: 1.4848x; 1.4848x over previous
//
#include <hip/hip_runtime.h>
#include <math.h>

// Problem constants
#define B_SZ   1024
#define H_SZ   512
#define E_SZ   100
#define L_SZ   128
#define KX     128          // embedding width padded 100 -> 128
#define VOCAB  50000
#define KW     648          // LDS weight row stride (fp16): 640 + 8 pad

typedef _Float16 f16x8 __attribute__((ext_vector_type(8)));
typedef float    f32x4 __attribute__((ext_vector_type(4)));

#define MFMA16(a, b, c) __builtin_amdgcn_mfma_f32_16x16x32_f16((a), (b), (c), 0, 0, 0)

__device__ __forceinline__ float fast_sigmoid(float x) {
    return __builtin_amdgcn_rcpf(1.0f + __expf(-x));
}
__device__ __forceinline__ float fast_tanh(float x) {
    return 1.0f - 2.0f * __builtin_amdgcn_rcpf(1.0f + __expf(2.0f * x));
}

// sc1 write-through store (device/LLC coherent) -- proven correct R5-R7.
__device__ __forceinline__ void store_h1(_Float16* p, float v) {
    union { unsigned short s; _Float16 h; } u; u.h = (_Float16)v;
    __hip_atomic_store((unsigned short*)p, u.s,
                       __ATOMIC_RELAXED, __HIP_MEMORY_SCOPE_AGENT);
}

// R8 KEY CHANGE: NON-ATOMIC sc1 loads via inline asm.
// The __hip_atomic_load path (R5-R7) emits atomic VMEM ops which the backend
// refuses to pipeline (atomics are unreorderable side-effecting ops) ->
// ~32 serialized ~900cyc LLC round trips per step = the invariant ~15us.
// Raw global_load_dwordx4 with the SAME sc1 scope bit has identical cache
// behavior (LLC-read-through, bypasses stale per-XCD L2) but is a plain
// load: 16 issued back-to-back in ONE asm block, ONE s_waitcnt vmcnt(0).
// "memory" clobber pins the block after the barrier spin; register deps
// pin it before the consuming MFMAs.
#define LOAD_H_HALF(A0, A1, P0, P1)                                         \
    asm volatile(                                                           \
        "global_load_dwordx4 %0,  %16, off sc1\n\t"                         \
        "global_load_dwordx4 %1,  %16, off offset:64 sc1\n\t"               \
        "global_load_dwordx4 %2,  %16, off offset:128 sc1\n\t"              \
        "global_load_dwordx4 %3,  %16, off offset:192 sc1\n\t"              \
        "global_load_dwordx4 %4,  %16, off offset:256 sc1\n\t"              \
        "global_load_dwordx4 %5,  %16, off offset:320 sc1\n\t"              \
        "global_load_dwordx4 %6,  %16, off offset:384 sc1\n\t"              \
        "global_load_dwordx4 %7,  %16, off offset:448 sc1\n\t"              \
        "global_load_dwordx4 %8,  %17, off sc1\n\t"                         \
        "global_load_dwordx4 %9,  %17, off offset:64 sc1\n\t"               \
        "global_load_dwordx4 %10, %17, off offset:128 sc1\n\t"              \
        "global_load_dwordx4 %11, %17, off offset:192 sc1\n\t"              \
        "global_load_dwordx4 %12, %17, off offset:256 sc1\n\t"              \
        "global_load_dwordx4 %13, %17, off offset:320 sc1\n\t"              \
        "global_load_dwordx4 %14, %17, off offset:384 sc1\n\t"              \
        "global_load_dwordx4 %15, %17, off offset:448 sc1\n\t"              \
        "s_waitcnt vmcnt(0)"                                                \
        : "=v"(A0[0]), "=v"(A0[1]), "=v"(A0[2]), "=v"(A0[3]),               \
          "=v"(A0[4]), "=v"(A0[5]), "=v"(A0[6]), "=v"(A0[7]),               \
          "=v"(A1[0]), "=v"(A1[1]), "=v"(A1[2]), "=v"(A1[3]),               \
          "=v"(A1[4]), "=v"(A1[5]), "=v"(A1[6]), "=v"(A1[7])                \
        : "v"(P0), "v"(P1)                                                  \
        : "memory")

// ---------------------------------------------------------------------------
// Convert embedding tables to fp16, pad rows 100 -> 128.
// ---------------------------------------------------------------------------
__global__ __launch_bounds__(256) void prep_emb_kernel(
    _Float16* __restrict__ ef_c, const float* __restrict__ e_c,
    _Float16* __restrict__ ef_r, const float* __restrict__ e_r)
{
    const int PER = VOCAB * KX;                // 6,400,000
    int idx = blockIdx.x * 256 + threadIdx.x;
    if (idx >= 2 * PER) return;
    const int gru = idx >= PER;
    const int local = gru ? idx - PER : idx;
    const int v = local >> 7;                  // /128
    const int e = local & 127;
    const float* src = gru ? e_r : e_c;
    _Float16* dst = gru ? ef_r : ef_c;
    dst[local] = (_Float16)(e < E_SZ ? src[v * E_SZ + e] : 0.0f);
}

// ---------------------------------------------------------------------------
// Persistent GRU kernel: all 128 time steps in ONE launch.
// 256 blocks x 512 threads = 2 GRUs x 8 m-tiles(128 rows) x 16 u-slices(32u).
// LDS 124,416 B -> 1 block/CU; weights staged to LDS once.
// h exchange: sc1 stores (write-through LLC) + sc1 PLAIN loads (asm, R8);
// group barrier = relaxed agent fetch_add + spin (no cache maintenance).
// ---------------------------------------------------------------------------
struct GruArgs {
    const float* Whh[2];
    const float* Wih[2];
    const float* bih[2];
    const float* bhh[2];
    const _Float16* emb[2];
    const int* idx[2];
    _Float16* hA;          // [2][1024][512] ping (h0 = 0, final h)
    _Float16* hB;          // [2][1024][512] pong
    unsigned int* bars;    // 16 groups, stride 32 uints (128B apart)
};

__global__ __launch_bounds__(512, 2) void gru_persistent(GruArgs args)
{
    const int blk = blockIdx.x;
    const int gru = blk >> 7;
    const int mt  = (blk >> 4) & 7;
    const int ut  = blk & 15;
    const int grp = (gru << 3) | mt;

    const float* __restrict__ Whh = args.Whh[gru];
    const float* __restrict__ Wih = args.Wih[gru];
    const float* __restrict__ bih = args.bih[gru];
    const float* __restrict__ bhh = args.bhh[gru];
    const _Float16* __restrict__ embf = args.emb[gru];
    const int* __restrict__ idx = args.idx[gru];

    const int u0 = ut * 32;        // block's hidden-unit base (32 units)
    const int mB = mt * 128;       // block's batch-row base (128 rows)

    __shared__ _Float16 Wl[3][32][KW];   // 124,416 B

    // ---- stage weights fp32 -> fp16 into LDS (once) ----
    for (int r = 0; r < 96; ++r) {            // r = gate*32 + uu
        const int g = r >> 5, uu = r & 31;
        const int row = g * H_SZ + u0 + uu;
        for (int k = threadIdx.x; k < KW; k += 512) {
            float v = 0.0f;
            if (k < H_SZ)                 v = Whh[row * H_SZ + k];
            else if (k < H_SZ + E_SZ)     v = Wih[row * E_SZ + (k - H_SZ)];
            Wl[g][uu][k] = (_Float16)v;
        }
    }
    __syncthreads();

    const int lane = threadIdx.x & 63;
    const int wave = threadIdx.x >> 6;   // 0..7
    const int lr   = lane & 15;          // fragment row
    const int kseg = lane >> 4;          // 0..3
    const int mw   = mB + (wave >> 1) * 32;  // wave's 32-row batch base
    const int uw   = (wave & 1) * 16;        // wave's 16-u half of block slice

    // bias preload (wave covers 16 fixed u's)
    const int ucol = u0 + uw + lr;
    const float bir  = bih[ucol]             + bhh[ucol];
    const float biz  = bih[H_SZ + ucol]      + bhh[H_SZ + ucol];
    const float binn = bih[2 * H_SZ + ucol];
    const float bhn  = bhh[2 * H_SZ + ucol];

    _Float16* hbuf0 = args.hA + (size_t)gru * B_SZ * H_SZ;
    _Float16* hbuf1 = args.hB + (size_t)gru * B_SZ * H_SZ;
    unsigned int* bar = args.bars + grp * 32;

    // h_prev at this thread's own output coordinates, carried in registers.
    float hreg[2][4] = {{0.f,0.f,0.f,0.f},{0.f,0.f,0.f,0.f}};

#pragma unroll 1
    for (int step = 0; step < L_SZ; ++step) {
        const _Float16* __restrict__ hin = (step & 1) ? hbuf1 : hbuf0;
        _Float16* __restrict__ hout      = (step & 1) ? hbuf0 : hbuf1;
        const int lcol = L_SZ - 1 - step;

        f32x4 accr[2], accz[2], acchn[2], accin[2];
#pragma unroll
        for (int i = 0; i < 2; i++) {
            accr[i]  = (f32x4){0.f, 0.f, 0.f, 0.f};
            accz[i]  = (f32x4){0.f, 0.f, 0.f, 0.f};
            acchn[i] = (f32x4){0.f, 0.f, 0.f, 0.f};
            accin[i] = (f32x4){0.f, 0.f, 0.f, 0.f};
        }

        // ---- x-part first (emb only -- independent of h(step)) ----
        const int iv0 = idx[(mw + lr) * L_SZ + lcol];
        const int iv1 = idx[(mw + 16 + lr) * L_SZ + lcol];
#pragma unroll
        for (int xc = 0; xc < 4; ++xc) {
            const int e0 = xc * 32 + kseg * 8;
            f16x8 a0 = *(const f16x8*)(embf + (size_t)iv0 * KX + e0);
            f16x8 a1 = *(const f16x8*)(embf + (size_t)iv1 * KX + e0);
            f16x8 b0 = *(const f16x8*)&Wl[0][uw + lr][H_SZ + e0];
            f16x8 b1 = *(const f16x8*)&Wl[1][uw + lr][H_SZ + e0];
            f16x8 b2 = *(const f16x8*)&Wl[2][uw + lr][H_SZ + e0];
            accr[0]  = MFMA16(a0, b0, accr[0]);
            accr[1]  = MFMA16(a1, b0, accr[1]);
            accz[0]  = MFMA16(a0, b1, accz[0]);
            accz[1]  = MFMA16(a1, b1, accz[1]);
            accin[0] = MFMA16(a0, b2, accin[0]);
            accin[1] = MFMA16(a1, b2, accin[1]);
        }

        // ---- wait for h(step) (group = 16 blocks sharing this m-tile) ----
        if (step > 0) {
            if (threadIdx.x == 0) {
                const unsigned tgt = 16u * (unsigned)step;
                while (__hip_atomic_load(bar, __ATOMIC_RELAXED,
                                         __HIP_MEMORY_SCOPE_AGENT) < tgt)
                    __builtin_amdgcn_s_sleep(1);
            }
            __syncthreads();
        }

        // ---- h-part: K = 512 in two half-passes.
        // Each half: ONE asm block = 16 pipelined sc1 loads + single
        // s_waitcnt vmcnt(0), then 48 MFMAs. ----
        const _Float16* hrow0 = hin + (mw + lr) * H_SZ + kseg * 8;
        const _Float16* hrow1 = hin + (mw + 16 + lr) * H_SZ + kseg * 8;
#pragma unroll
        for (int half = 0; half < 2; ++half) {
            const int kbase = half * 256;
            f16x8 a0[8], a1[8];
            LOAD_H_HALF(a0, a1, hrow0 + kbase, hrow1 + kbase);
#pragma unroll
            for (int kc = 0; kc < 8; ++kc) {
                const int k0 = kbase + kc * 32 + kseg * 8;
                f16x8 b0 = *(const f16x8*)&Wl[0][uw + lr][k0];
                f16x8 b1 = *(const f16x8*)&Wl[1][uw + lr][k0];
                f16x8 b2 = *(const f16x8*)&Wl[2][uw + lr][k0];
                accr[0]  = MFMA16(a0[kc], b0, accr[0]);
                accr[1]  = MFMA16(a1[kc], b0, accr[1]);
                accz[0]  = MFMA16(a0[kc], b1, accz[0]);
                accz[1]  = MFMA16(a1[kc], b1, accz[1]);
                acchn[0] = MFMA16(a0[kc], b2, acchn[0]);
                acchn[1] = MFMA16(a1[kc], b2, acchn[1]);
            }
        }

        // ---- epilogue: gates + state update (sc1 write-through stores) ----
        // C/D layout: col = lane&15 (u), row = (lane>>4)*4 + reg (m)
#pragma unroll
        for (int mt2 = 0; mt2 < 2; ++mt2) {
#pragma unroll
            for (int r = 0; r < 4; ++r) {
                const int m = mw + mt2 * 16 + kseg * 4 + r;
                const float rg = fast_sigmoid(accr[mt2][r] + bir);
                const float zg = fast_sigmoid(accz[mt2][r] + biz);
                const float ng = fast_tanh(accin[mt2][r] + binn +
                                           rg * (acchn[mt2][r] + bhn));
                float nh = (1.0f - zg) * ng + zg * hreg[mt2][r];
                nh = (float)(_Float16)nh;       // bit-match the stored fp16
                hreg[mt2][r] = nh;
                store_h1(hout + m * H_SZ + ucol, nh);
            }
        }

        // ---- publish (RELAXED: no buffer_wbl2) ----
        if (step + 1 < L_SZ) {
            __syncthreads();   // emits s_waitcnt vmcnt(0): all sc1 stores acked
            if (threadIdx.x == 0) {
                __hip_atomic_fetch_add(bar, 1u, __ATOMIC_RELAXED,
                                       __HIP_MEMORY_SCOPE_AGENT);
            }
        }
    }
    // final h (step 127, odd) landed in hA via sc1 stores; the end-of-kernel
    // system-scope release makes it visible to the scores kernel.
}

// ---------------------------------------------------------------------------
// scores = hc @ hr^T (fp16 in, fp32 out), MFMA. Block 64x64, wave 32x32.
// ---------------------------------------------------------------------------
__global__ __launch_bounds__(256, 1) void scores_kernel(
    const _Float16* __restrict__ hc, const _Float16* __restrict__ hr,
    float* __restrict__ out)
{
    const int lane = threadIdx.x & 63;
    const int wave = threadIdx.x >> 6;
    const int lr   = lane & 15;
    const int kseg = lane >> 4;
    const int m0 = blockIdx.y * 64 + (wave >> 1) * 32;
    const int n0 = blockIdx.x * 64 + (wave & 1) * 32;

    f32x4 acc[2][2];
#pragma unroll
    for (int i = 0; i < 2; i++)
#pragma unroll
        for (int j = 0; j < 2; j++)
            acc[i][j] = (f32x4){0.f, 0.f, 0.f, 0.f};

#pragma unroll 2
    for (int kc = 0; kc < 16; kc++) {
        const int k0 = kc * 32 + kseg * 8;
        f16x8 a[2], b[2];
#pragma unroll
        for (int mt = 0; mt < 2; mt++)
            a[mt] = *(const f16x8*)(hc + (m0 + mt * 16 + lr) * H_SZ + k0);
#pragma unroll
        for (int nt = 0; nt < 2; nt++)
            b[nt] = *(const f16x8*)(hr + (n0 + nt * 16 + lr) * H_SZ + k0);
#pragma unroll
        for (int mt = 0; mt < 2; mt++)
#pragma unroll
            for (int nt = 0; nt < 2; nt++)
                acc[mt][nt] = MFMA16(a[mt], b[nt], acc[mt][nt]);
    }

#pragma unroll
    for (int mt = 0; mt < 2; mt++)
#pragma unroll
        for (int nt = 0; nt < 2; nt++)
#pragma unroll
            for (int r = 0; r < 4; r++) {
                const int m = m0 + mt * 16 + kseg * 4 + r;
                const int n = n0 + nt * 16 + lr;
                out[m * B_SZ + n] = acc[mt][nt][r];
            }
}

// In-place row softmax on [1024, 1024]; one block per row.
__global__ __launch_bounds__(256) void softmax_kernel(float* __restrict__ out)
{
    const int row = blockIdx.x;
    float* p = out + (size_t)row * B_SZ;
    const int t = threadIdx.x;
    const int wave = t >> 6;
    const int lane = t & 63;

    float4 v = ((const float4*)p)[t];
    float m = fmaxf(fmaxf(v.x, v.y), fmaxf(v.z, v.w));
#pragma unroll
    for (int off = 32; off >= 1; off >>= 1)
        m = fmaxf(m, __shfl_xor(m, off, 64));

    __shared__ float redm[4];
    if (lane == 0) redm[wave] = m;
    __syncthreads();
    m = fmaxf(fmaxf(redm[0], redm[1]), fmaxf(redm[2], redm[3]));

    const float e0 = __expf(v.x - m);
    const float e1 = __expf(v.y - m);
    const float e2 = __expf(v.z - m);
    const float e3 = __expf(v.w - m);
    float s = e0 + e1 + e2 + e3;
#pragma unroll
    for (int off = 32; off >= 1; off >>= 1)
        s += __shfl_xor(s, off, 64);

    __shared__ float reds[4];
    if (lane == 0) reds[wave] = s;
    __syncthreads();
    s = reds[0] + reds[1] + reds[2] + reds[3];

    const float inv = 1.0f / s;
    float4 o;
    o.x = e0 * inv; o.y = e1 * inv; o.z = e2 * inv; o.w = e3 * inv;
    ((float4*)p)[t] = o;
}

extern "C" void kernel_launch(void* const* d_in, const int* in_sizes, int n_in,
                              void* d_out, int out_size, void* d_ws, size_t ws_size,
                              hipStream_t stream)
{
    (void)in_sizes; (void)n_in; (void)out_size; (void)ws_size;

    const int*   contexts = (const int*)d_in[0];
    const int*   replies  = (const int*)d_in[1];
    const float* ctx_emb  = (const float*)d_in[2];
    const float* ctx_Wih  = (const float*)d_in[3];
    const float* ctx_Whh  = (const float*)d_in[4];
    const float* ctx_bih  = (const float*)d_in[5];
    const float* ctx_bhh  = (const float*)d_in[6];
    const float* rep_emb  = (const float*)d_in[7];
    const float* rep_Wih  = (const float*)d_in[8];
    const float* rep_Whh  = (const float*)d_in[9];
    const float* rep_bih  = (const float*)d_in[10];
    const float* rep_bhh  = (const float*)d_in[11];
    float* out = (float*)d_out;

    // ---- workspace layout (fp16 elements) ----
    const size_t EMB_ELEMS = (size_t)VOCAB * KX;          // 6,400,000
    const size_t H_ELEMS   = (size_t)B_SZ * H_SZ;         // 524,288

    _Float16* base   = (_Float16*)d_ws;
    _Float16* embf_c = base;
    _Float16* embf_r = embf_c + EMB_ELEMS;
    _Float16* hB     = embf_r + EMB_ELEMS;     // pong [2][B][H]
    _Float16* hA     = hB + 2 * H_ELEMS;       // ping [2][B][H]
    unsigned int* bars = (unsigned int*)(hA + 2 * H_ELEMS);  // 16*32 uints

    // zero h0 (both GRUs, ping buffer) AND the barrier counters in one shot.
    hipMemsetAsync(hA, 0, 2 * H_ELEMS * sizeof(_Float16) + 16 * 32 * sizeof(unsigned int), stream);

    // embedding tables fp32 -> fp16 (padded to 128)
    {
        const int total_emb = 2 * (int)EMB_ELEMS;
        prep_emb_kernel<<<(total_emb + 255) / 256, 256, 0, stream>>>(
            embf_c, ctx_emb, embf_r, rep_emb);
    }

    // one persistent kernel for all 128 GRU steps (both GRUs)
    GruArgs a;
    a.Whh[0] = ctx_Whh; a.Whh[1] = rep_Whh;
    a.Wih[0] = ctx_Wih; a.Wih[1] = rep_Wih;
    a.bih[0] = ctx_bih; a.bih[1] = rep_bih;
    a.bhh[0] = ctx_bhh; a.bhh[1] = rep_bhh;
    a.emb[0] = embf_c;  a.emb[1] = embf_r;
    a.idx[0] = contexts; a.idx[1] = replies;
    a.hA = hA; a.hB = hB; a.bars = bars;
    gru_persistent<<<dim3(256), dim3(512), 0, stream>>>(a);

    // final states: gru0 (ctx) at hA, gru1 (rep) at hA + B*H
    scores_kernel<<<dim3(B_SZ / 64, B_SZ / 64), 256, 0, stream>>>(hA, hA + H_ELEMS, out);
    softmax_kernel<<<B_SZ, 256, 0, stream>>>(out);
}

// Round 9
// 1384.455 us; speedup vs baseline: 1.8475x; 1.2443x over previous
//
#include <hip/hip_runtime.h>
#include <math.h>

// Problem constants
#define B_SZ   1024
#define H_SZ   512
#define E_SZ   100
#define L_SZ   128
#define KX     128          // embedding width padded 100 -> 128
#define VOCAB  50000
#define KW     648          // LDS weight row stride (fp16): 640 + 8 pad

typedef _Float16 f16x8 __attribute__((ext_vector_type(8)));
typedef float    f32x4 __attribute__((ext_vector_type(4)));

#define MFMA16(a, b, c) __builtin_amdgcn_mfma_f32_16x16x32_f16((a), (b), (c), 0, 0, 0)

__device__ __forceinline__ float fast_sigmoid(float x) {
    return __builtin_amdgcn_rcpf(1.0f + __expf(-x));
}
__device__ __forceinline__ float fast_tanh(float x) {
    return 1.0f - 2.0f * __builtin_amdgcn_rcpf(1.0f + __expf(2.0f * x));
}

// sc1 write-through store (device/LLC coherent) -- proven correct R5-R8.
__device__ __forceinline__ void store_h1(_Float16* p, float v) {
    union { unsigned short s; _Float16 h; } u; u.h = (_Float16)v;
    __hip_atomic_store((unsigned short*)p, u.s,
                       __ATOMIC_RELAXED, __HIP_MEMORY_SCOPE_AGENT);
}

// ---------------------------------------------------------------------------
// Convert embedding tables to fp16, pad rows 100 -> 128.
// ---------------------------------------------------------------------------
__global__ __launch_bounds__(256) void prep_emb_kernel(
    _Float16* __restrict__ ef_c, const float* __restrict__ e_c,
    _Float16* __restrict__ ef_r, const float* __restrict__ e_r)
{
    const int PER = VOCAB * KX;                // 6,400,000
    int idx = blockIdx.x * 256 + threadIdx.x;
    if (idx >= 2 * PER) return;
    const int gru = idx >= PER;
    const int local = gru ? idx - PER : idx;
    const int v = local >> 7;                  // /128
    const int e = local & 127;
    const float* src = gru ? e_r : e_c;
    _Float16* dst = gru ? ef_r : ef_c;
    dst[local] = (_Float16)(e < E_SZ ? src[v * E_SZ + e] : 0.0f);
}

// ---------------------------------------------------------------------------
// Persistent GRU kernel: all 128 time steps in ONE launch.
// 256 blocks x 256 threads = 2 GRUs x 8 m-tiles(128 rows) x 16 u-slices(32u).
// R9: wave tile = 32m x 32u x FULL K (4 waves, no A duplication).
//   R8's 8-wave tiling had wave pairs loading identical A slabs -> 64 MB/step
//   chip-wide LLC read traffic. This tiling loads each A byte once per block:
//   32 MB/step. TLP loss known-negligible (R3 vs R4: 4 vs 8 waves ~= equal).
// With 1 wave/SIMD the VGPR budget is 512 -> the whole K=512 A-slab is
// batched in ONE asm block (32 pipelined sc1 loads, single vmcnt(0)).
// h exchange: sc1 stores (write-through LLC) + plain sc1 asm loads;
// group barrier = relaxed agent fetch_add + spin (no cache maintenance).
// ---------------------------------------------------------------------------
struct GruArgs {
    const float* Whh[2];
    const float* Wih[2];
    const float* bih[2];
    const float* bhh[2];
    const _Float16* emb[2];
    const int* idx[2];
    _Float16* hA;          // [2][1024][512] ping (h0 = 0, final h)
    _Float16* hB;          // [2][1024][512] pong
    unsigned int* bars;    // 16 groups, stride 32 uints (128B apart)
};

__global__ __launch_bounds__(256, 1) void gru_persistent(GruArgs args)
{
    const int blk = blockIdx.x;
    const int gru = blk >> 7;
    const int mt  = (blk >> 4) & 7;
    const int ut  = blk & 15;
    const int grp = (gru << 3) | mt;

    const float* __restrict__ Whh = args.Whh[gru];
    const float* __restrict__ Wih = args.Wih[gru];
    const float* __restrict__ bih = args.bih[gru];
    const float* __restrict__ bhh = args.bhh[gru];
    const _Float16* __restrict__ embf = args.emb[gru];
    const int* __restrict__ idx = args.idx[gru];

    const int u0 = ut * 32;        // block's hidden-unit base (32 units)
    const int mB = mt * 128;       // block's batch-row base (128 rows)

    __shared__ _Float16 Wl[3][32][KW];   // 124,416 B

    // ---- stage weights fp32 -> fp16 into LDS (once) ----
    for (int r = 0; r < 96; ++r) {            // r = gate*32 + uu
        const int g = r >> 5, uu = r & 31;
        const int row = g * H_SZ + u0 + uu;
        for (int k = threadIdx.x; k < KW; k += 256) {
            float v = 0.0f;
            if (k < H_SZ)                 v = Whh[row * H_SZ + k];
            else if (k < H_SZ + E_SZ)     v = Wih[row * E_SZ + (k - H_SZ)];
            Wl[g][uu][k] = (_Float16)v;
        }
    }
    __syncthreads();

    const int lane = threadIdx.x & 63;
    const int wave = threadIdx.x >> 6;   // 0..3
    const int lr   = lane & 15;          // fragment row
    const int kseg = lane >> 4;          // 0..3
    const int mw   = mB + wave * 32;     // wave's 32-row batch base

    // bias preload: this thread's two u columns (ut2 = 0,1)
    float bir[2], biz[2], binn[2], bhn[2];
    int ucol[2];
#pragma unroll
    for (int ut2 = 0; ut2 < 2; ++ut2) {
        ucol[ut2] = u0 + ut2 * 16 + lr;
        const int u = ucol[ut2];
        bir[ut2]  = bih[u]             + bhh[u];
        biz[ut2]  = bih[H_SZ + u]      + bhh[H_SZ + u];
        binn[ut2] = bih[2 * H_SZ + u];
        bhn[ut2]  = bhh[2 * H_SZ + u];
    }

    _Float16* hbuf0 = args.hA + (size_t)gru * B_SZ * H_SZ;
    _Float16* hbuf1 = args.hB + (size_t)gru * B_SZ * H_SZ;
    unsigned int* bar = args.bars + grp * 32;

    // h_prev at this thread's own output coordinates, carried in registers.
    float hreg[2][2][4] = {};   // [mt2][ut2][r]

#pragma unroll 1
    for (int step = 0; step < L_SZ; ++step) {
        const _Float16* __restrict__ hin = (step & 1) ? hbuf1 : hbuf0;
        _Float16* __restrict__ hout      = (step & 1) ? hbuf0 : hbuf1;
        const int lcol = L_SZ - 1 - step;

        f32x4 accr[2][2], accz[2][2], acchn[2][2], accin[2][2];
#pragma unroll
        for (int i = 0; i < 2; i++)
#pragma unroll
            for (int j = 0; j < 2; j++) {
                accr[i][j]  = (f32x4){0.f, 0.f, 0.f, 0.f};
                accz[i][j]  = (f32x4){0.f, 0.f, 0.f, 0.f};
                acchn[i][j] = (f32x4){0.f, 0.f, 0.f, 0.f};
                accin[i][j] = (f32x4){0.f, 0.f, 0.f, 0.f};
            }

        // ---- x-part first (emb only -- independent of h(step)) ----
        const int iv0 = idx[(mw + lr) * L_SZ + lcol];
        const int iv1 = idx[(mw + 16 + lr) * L_SZ + lcol];
#pragma unroll
        for (int xc = 0; xc < 4; ++xc) {
            const int e0 = xc * 32 + kseg * 8;
            f16x8 a0 = *(const f16x8*)(embf + (size_t)iv0 * KX + e0);
            f16x8 a1 = *(const f16x8*)(embf + (size_t)iv1 * KX + e0);
#pragma unroll
            for (int ut2 = 0; ut2 < 2; ++ut2) {
                f16x8 b0 = *(const f16x8*)&Wl[0][ut2 * 16 + lr][H_SZ + e0];
                f16x8 b1 = *(const f16x8*)&Wl[1][ut2 * 16 + lr][H_SZ + e0];
                f16x8 b2 = *(const f16x8*)&Wl[2][ut2 * 16 + lr][H_SZ + e0];
                accr[0][ut2]  = MFMA16(a0, b0, accr[0][ut2]);
                accr[1][ut2]  = MFMA16(a1, b0, accr[1][ut2]);
                accz[0][ut2]  = MFMA16(a0, b1, accz[0][ut2]);
                accz[1][ut2]  = MFMA16(a1, b1, accz[1][ut2]);
                accin[0][ut2] = MFMA16(a0, b2, accin[0][ut2]);
                accin[1][ut2] = MFMA16(a1, b2, accin[1][ut2]);
            }
        }

        // ---- wait for h(step) (group = 16 blocks sharing this m-tile) ----
        if (step > 0) {
            if (threadIdx.x == 0) {
                const unsigned tgt = 16u * (unsigned)step;
                while (__hip_atomic_load(bar, __ATOMIC_RELAXED,
                                         __HIP_MEMORY_SCOPE_AGENT) < tgt)
                    __builtin_amdgcn_s_sleep(1);
            }
            __syncthreads();
        }

        // ---- h-part A-slab: full K = 512 in ONE asm batch.
        // 32 pipelined sc1 (LLC-read-through) loads, single vmcnt(0). ----
        const _Float16* hrow0 = hin + (mw + lr) * H_SZ + kseg * 8;
        const _Float16* hrow1 = hin + (mw + 16 + lr) * H_SZ + kseg * 8;
        f16x8 a0h[16], a1h[16];
        asm volatile(
            "global_load_dwordx4 %0,  %32, off sc1\n\t"
            "global_load_dwordx4 %1,  %32, off offset:64 sc1\n\t"
            "global_load_dwordx4 %2,  %32, off offset:128 sc1\n\t"
            "global_load_dwordx4 %3,  %32, off offset:192 sc1\n\t"
            "global_load_dwordx4 %4,  %32, off offset:256 sc1\n\t"
            "global_load_dwordx4 %5,  %32, off offset:320 sc1\n\t"
            "global_load_dwordx4 %6,  %32, off offset:384 sc1\n\t"
            "global_load_dwordx4 %7,  %32, off offset:448 sc1\n\t"
            "global_load_dwordx4 %8,  %32, off offset:512 sc1\n\t"
            "global_load_dwordx4 %9,  %32, off offset:576 sc1\n\t"
            "global_load_dwordx4 %10, %32, off offset:640 sc1\n\t"
            "global_load_dwordx4 %11, %32, off offset:704 sc1\n\t"
            "global_load_dwordx4 %12, %32, off offset:768 sc1\n\t"
            "global_load_dwordx4 %13, %32, off offset:832 sc1\n\t"
            "global_load_dwordx4 %14, %32, off offset:896 sc1\n\t"
            "global_load_dwordx4 %15, %32, off offset:960 sc1\n\t"
            "global_load_dwordx4 %16, %33, off sc1\n\t"
            "global_load_dwordx4 %17, %33, off offset:64 sc1\n\t"
            "global_load_dwordx4 %18, %33, off offset:128 sc1\n\t"
            "global_load_dwordx4 %19, %33, off offset:192 sc1\n\t"
            "global_load_dwordx4 %20, %33, off offset:256 sc1\n\t"
            "global_load_dwordx4 %21, %33, off offset:320 sc1\n\t"
            "global_load_dwordx4 %22, %33, off offset:384 sc1\n\t"
            "global_load_dwordx4 %23, %33, off offset:448 sc1\n\t"
            "global_load_dwordx4 %24, %33, off offset:512 sc1\n\t"
            "global_load_dwordx4 %25, %33, off offset:576 sc1\n\t"
            "global_load_dwordx4 %26, %33, off offset:640 sc1\n\t"
            "global_load_dwordx4 %27, %33, off offset:704 sc1\n\t"
            "global_load_dwordx4 %28, %33, off offset:768 sc1\n\t"
            "global_load_dwordx4 %29, %33, off offset:832 sc1\n\t"
            "global_load_dwordx4 %30, %33, off offset:896 sc1\n\t"
            "global_load_dwordx4 %31, %33, off offset:960 sc1\n\t"
            "s_waitcnt vmcnt(0)"
            : "=&v"(a0h[0]),  "=&v"(a0h[1]),  "=&v"(a0h[2]),  "=&v"(a0h[3]),
              "=&v"(a0h[4]),  "=&v"(a0h[5]),  "=&v"(a0h[6]),  "=&v"(a0h[7]),
              "=&v"(a0h[8]),  "=&v"(a0h[9]),  "=&v"(a0h[10]), "=&v"(a0h[11]),
              "=&v"(a0h[12]), "=&v"(a0h[13]), "=&v"(a0h[14]), "=&v"(a0h[15]),
              "=&v"(a1h[0]),  "=&v"(a1h[1]),  "=&v"(a1h[2]),  "=&v"(a1h[3]),
              "=&v"(a1h[4]),  "=&v"(a1h[5]),  "=&v"(a1h[6]),  "=&v"(a1h[7]),
              "=&v"(a1h[8]),  "=&v"(a1h[9]),  "=&v"(a1h[10]), "=&v"(a1h[11]),
              "=&v"(a1h[12]), "=&v"(a1h[13]), "=&v"(a1h[14]), "=&v"(a1h[15])
            : "v"(hrow0), "v"(hrow1)
            : "memory");

        // ---- h-part MFMAs: 16 kc x 12 ----
#pragma unroll
        for (int kc = 0; kc < 16; ++kc) {
            const int k0 = kc * 32 + kseg * 8;
#pragma unroll
            for (int ut2 = 0; ut2 < 2; ++ut2) {
                f16x8 b0 = *(const f16x8*)&Wl[0][ut2 * 16 + lr][k0];
                f16x8 b1 = *(const f16x8*)&Wl[1][ut2 * 16 + lr][k0];
                f16x8 b2 = *(const f16x8*)&Wl[2][ut2 * 16 + lr][k0];
                accr[0][ut2]  = MFMA16(a0h[kc], b0, accr[0][ut2]);
                accr[1][ut2]  = MFMA16(a1h[kc], b0, accr[1][ut2]);
                accz[0][ut2]  = MFMA16(a0h[kc], b1, accz[0][ut2]);
                accz[1][ut2]  = MFMA16(a1h[kc], b1, accz[1][ut2]);
                acchn[0][ut2] = MFMA16(a0h[kc], b2, acchn[0][ut2]);
                acchn[1][ut2] = MFMA16(a1h[kc], b2, acchn[1][ut2]);
            }
        }

        // ---- epilogue: gates + state update (sc1 write-through stores) ----
        // C/D layout: col = lane&15 (u), row = (lane>>4)*4 + reg (m)
#pragma unroll
        for (int mt2 = 0; mt2 < 2; ++mt2) {
#pragma unroll
            for (int ut2 = 0; ut2 < 2; ++ut2) {
#pragma unroll
                for (int r = 0; r < 4; ++r) {
                    const int m = mw + mt2 * 16 + kseg * 4 + r;
                    const float rg = fast_sigmoid(accr[mt2][ut2][r] + bir[ut2]);
                    const float zg = fast_sigmoid(accz[mt2][ut2][r] + biz[ut2]);
                    const float ng = fast_tanh(accin[mt2][ut2][r] + binn[ut2] +
                                               rg * (acchn[mt2][ut2][r] + bhn[ut2]));
                    float nh = (1.0f - zg) * ng + zg * hreg[mt2][ut2][r];
                    nh = (float)(_Float16)nh;   // bit-match the stored fp16
                    hreg[mt2][ut2][r] = nh;
                    store_h1(hout + m * H_SZ + ucol[ut2], nh);
                }
            }
        }

        // ---- publish (RELAXED: no buffer_wbl2) ----
        if (step + 1 < L_SZ) {
            __syncthreads();   // emits s_waitcnt vmcnt(0): all sc1 stores acked
            if (threadIdx.x == 0) {
                __hip_atomic_fetch_add(bar, 1u, __ATOMIC_RELAXED,
                                       __HIP_MEMORY_SCOPE_AGENT);
            }
        }
    }
    // final h (step 127, odd) landed in hA via sc1 stores; the end-of-kernel
    // system-scope release makes it visible to the scores kernel.
}

// ---------------------------------------------------------------------------
// scores = hc @ hr^T (fp16 in, fp32 out), MFMA. Block 64x64, wave 32x32.
// ---------------------------------------------------------------------------
__global__ __launch_bounds__(256, 1) void scores_kernel(
    const _Float16* __restrict__ hc, const _Float16* __restrict__ hr,
    float* __restrict__ out)
{
    const int lane = threadIdx.x & 63;
    const int wave = threadIdx.x >> 6;
    const int lr   = lane & 15;
    const int kseg = lane >> 4;
    const int m0 = blockIdx.y * 64 + (wave >> 1) * 32;
    const int n0 = blockIdx.x * 64 + (wave & 1) * 32;

    f32x4 acc[2][2];
#pragma unroll
    for (int i = 0; i < 2; i++)
#pragma unroll
        for (int j = 0; j < 2; j++)
            acc[i][j] = (f32x4){0.f, 0.f, 0.f, 0.f};

#pragma unroll 2
    for (int kc = 0; kc < 16; kc++) {
        const int k0 = kc * 32 + kseg * 8;
        f16x8 a[2], b[2];
#pragma unroll
        for (int mt = 0; mt < 2; mt++)
            a[mt] = *(const f16x8*)(hc + (m0 + mt * 16 + lr) * H_SZ + k0);
#pragma unroll
        for (int nt = 0; nt < 2; nt++)
            b[nt] = *(const f16x8*)(hr + (n0 + nt * 16 + lr) * H_SZ + k0);
#pragma unroll
        for (int mt = 0; mt < 2; mt++)
#pragma unroll
            for (int nt = 0; nt < 2; nt++)
                acc[mt][nt] = MFMA16(a[mt], b[nt], acc[mt][nt]);
    }

#pragma unroll
    for (int mt = 0; mt < 2; mt++)
#pragma unroll
        for (int nt = 0; nt < 2; nt++)
#pragma unroll
            for (int r = 0; r < 4; r++) {
                const int m = m0 + mt * 16 + kseg * 4 + r;
                const int n = n0 + nt * 16 + lr;
                out[m * B_SZ + n] = acc[mt][nt][r];
            }
}

// In-place row softmax on [1024, 1024]; one block per row.
__global__ __launch_bounds__(256) void softmax_kernel(float* __restrict__ out)
{
    const int row = blockIdx.x;
    float* p = out + (size_t)row * B_SZ;
    const int t = threadIdx.x;
    const int wave = t >> 6;
    const int lane = t & 63;

    float4 v = ((const float4*)p)[t];
    float m = fmaxf(fmaxf(v.x, v.y), fmaxf(v.z, v.w));
#pragma unroll
    for (int off = 32; off >= 1; off >>= 1)
        m = fmaxf(m, __shfl_xor(m, off, 64));

    __shared__ float redm[4];
    if (lane == 0) redm[wave] = m;
    __syncthreads();
    m = fmaxf(fmaxf(redm[0], redm[1]), fmaxf(redm[2], redm[3]));

    const float e0 = __expf(v.x - m);
    const float e1 = __expf(v.y - m);
    const float e2 = __expf(v.z - m);
    const float e3 = __expf(v.w - m);
    float s = e0 + e1 + e2 + e3;
#pragma unroll
    for (int off = 32; off >= 1; off >>= 1)
        s += __shfl_xor(s, off, 64);

    __shared__ float reds[4];
    if (lane == 0) reds[wave] = s;
    __syncthreads();
    s = reds[0] + reds[1] + reds[2] + reds[3];

    const float inv = 1.0f / s;
    float4 o;
    o.x = e0 * inv; o.y = e1 * inv; o.z = e2 * inv; o.w = e3 * inv;
    ((float4*)p)[t] = o;
}

extern "C" void kernel_launch(void* const* d_in, const int* in_sizes, int n_in,
                              void* d_out, int out_size, void* d_ws, size_t ws_size,
                              hipStream_t stream)
{
    (void)in_sizes; (void)n_in; (void)out_size; (void)ws_size;

    const int*   contexts = (const int*)d_in[0];
    const int*   replies  = (const int*)d_in[1];
    const float* ctx_emb  = (const float*)d_in[2];
    const float* ctx_Wih  = (const float*)d_in[3];
    const float* ctx_Whh  = (const float*)d_in[4];
    const float* ctx_bih  = (const float*)d_in[5];
    const float* ctx_bhh  = (const float*)d_in[6];
    const float* rep_emb  = (const float*)d_in[7];
    const float* rep_Wih  = (const float*)d_in[8];
    const float* rep_Whh  = (const float*)d_in[9];
    const float* rep_bih  = (const float*)d_in[10];
    const float* rep_bhh  = (const float*)d_in[11];
    float* out = (float*)d_out;

    // ---- workspace layout (fp16 elements) ----
    const size_t EMB_ELEMS = (size_t)VOCAB * KX;          // 6,400,000
    const size_t H_ELEMS   = (size_t)B_SZ * H_SZ;         // 524,288

    _Float16* base   = (_Float16*)d_ws;
    _Float16* embf_c = base;
    _Float16* embf_r = embf_c + EMB_ELEMS;
    _Float16* hB     = embf_r + EMB_ELEMS;     // pong [2][B][H]
    _Float16* hA     = hB + 2 * H_ELEMS;       // ping [2][B][H]
    unsigned int* bars = (unsigned int*)(hA + 2 * H_ELEMS);  // 16*32 uints

    // zero h0 (both GRUs, ping buffer) AND the barrier counters in one shot.
    hipMemsetAsync(hA, 0, 2 * H_ELEMS * sizeof(_Float16) + 16 * 32 * sizeof(unsigned int), stream);

    // embedding tables fp32 -> fp16 (padded to 128)
    {
        const int total_emb = 2 * (int)EMB_ELEMS;
        prep_emb_kernel<<<(total_emb + 255) / 256, 256, 0, stream>>>(
            embf_c, ctx_emb, embf_r, rep_emb);
    }

    // one persistent kernel for all 128 GRU steps (both GRUs)
    GruArgs a;
    a.Whh[0] = ctx_Whh; a.Whh[1] = rep_Whh;
    a.Wih[0] = ctx_Wih; a.Wih[1] = rep_Wih;
    a.bih[0] = ctx_bih; a.bih[1] = rep_bih;
    a.bhh[0] = ctx_bhh; a.bhh[1] = rep_bhh;
    a.emb[0] = embf_c;  a.emb[1] = embf_r;
    a.idx[0] = contexts; a.idx[1] = replies;
    a.hA = hA; a.hB = hB; a.bars = bars;
    gru_persistent<<<dim3(256), dim3(256), 0, stream>>>(a);

    // final states: gru0 (ctx) at hA, gru1 (rep) at hA + B*H
    scores_kernel<<<dim3(B_SZ / 64, B_SZ / 64), 256, 0, stream>>>(hA, hA + H_ELEMS, out);
    softmax_kernel<<<B_SZ, 256, 0, stream>>>(out);
}

// Round 10
// 1327.591 us; speedup vs baseline: 1.9266x; 1.0428x over previous
//
#include <hip/hip_runtime.h>
#include <math.h>

// Problem constants
#define B_SZ   1024
#define H_SZ   512
#define E_SZ   100
#define L_SZ   128
#define KX     128          // embedding width padded 100 -> 128
#define VOCAB  50000
#define KW     648          // LDS weight row stride (fp16): 640 + 8 pad

typedef _Float16 f16x8 __attribute__((ext_vector_type(8)));
typedef float    f32x4 __attribute__((ext_vector_type(4)));

#define MFMA16(a, b, c) __builtin_amdgcn_mfma_f32_16x16x32_f16((a), (b), (c), 0, 0, 0)

__device__ __forceinline__ float fast_sigmoid(float x) {
    return __builtin_amdgcn_rcpf(1.0f + __expf(-x));
}
__device__ __forceinline__ float fast_tanh(float x) {
    return 1.0f - 2.0f * __builtin_amdgcn_rcpf(1.0f + __expf(2.0f * x));
}

// ---------------------------------------------------------------------------
// Convert embedding tables to fp16, pad rows 100 -> 128.
// ---------------------------------------------------------------------------
__global__ __launch_bounds__(256) void prep_emb_kernel(
    _Float16* __restrict__ ef_c, const float* __restrict__ e_c,
    _Float16* __restrict__ ef_r, const float* __restrict__ e_r)
{
    const int PER = VOCAB * KX;                // 6,400,000
    int idx = blockIdx.x * 256 + threadIdx.x;
    if (idx >= 2 * PER) return;
    const int gru = idx >= PER;
    const int local = gru ? idx - PER : idx;
    const int v = local >> 7;                  // /128
    const int e = local & 127;
    const float* src = gru ? e_r : e_c;
    _Float16* dst = gru ? ef_r : ef_c;
    dst[local] = (_Float16)(e < E_SZ ? src[v * E_SZ + e] : 0.0f);
}

// ---------------------------------------------------------------------------
// Persistent GRU kernel: all 128 time steps in ONE launch.
//
// R10: XCD-LOCAL GROUPS. A group (gru, m-tile) = 16 blocks whose h dataflow
// is closed (they write the m-tile and are its only readers next step).
// Each block discovers its XCD via s_getreg(HW_REG_XCC_ID) and claims a slot
// on a per-XCD counter; roles are assigned so each group lives entirely on
// ONE XCD (1 block/CU from 124KB LDS + proven all-256 co-residency => exactly
// 32 blocks/XCD). h then moves through the XCD's L2 (~200cyc, 4.3TB/s/XCD):
//   stores: plain (dirty lines in local L2)
//   loads : sc0 asm batch (bypass L1 -- R8/R9 proved sc1 = bypass L1+L2,
//           hierarchical bits => sc0 = bypass L1 only), 32 loads, 1 vmcnt.
// The LLC is no longer in the per-step data path (was 32MB/step round trips).
// Barrier: unchanged from R9 (relaxed agent fetch_add + spin at LLC, proven).
// Cross-dispatch visibility (h0 memset in, final h out): dispatch-boundary
// release/acquire (empirically proven by R2's per-step-kernel correctness).
// ---------------------------------------------------------------------------
struct GruArgs {
    const float* Whh[2];
    const float* Wih[2];
    const float* bih[2];
    const float* bhh[2];
    const _Float16* emb[2];
    const int* idx[2];
    _Float16* hA;          // [2][1024][512] ping (h0 = 0, final h)
    _Float16* hB;          // [2][1024][512] pong
    unsigned int* bars;    // 16 groups, stride 32 uints (128B apart)
    unsigned int* claim;   // 8 per-XCD slot counters
};

__global__ __launch_bounds__(256, 1) void gru_persistent(GruArgs args)
{
    // ---- XCD discovery + role claim (once per block) ----
    __shared__ int role_s;
    if (threadIdx.x == 0) {
        unsigned xcd;
        asm volatile("s_getreg_b32 %0, hwreg(HW_REG_XCC_ID)" : "=s"(xcd));
        xcd &= 7u;
        unsigned slot = atomicAdd(&args.claim[xcd], 1u);   // device-scope
        role_s = (int)(xcd * 32u + slot);
    }
    __syncthreads();
    const int role = role_s;
    const int grp  = role >> 4;    // 0..15  (2 groups per XCD, XCD-local)
    const int ut   = role & 15;    // u-slice within group
    const int gru  = grp >> 3;
    const int mt   = grp & 7;

    const float* __restrict__ Whh = args.Whh[gru];
    const float* __restrict__ Wih = args.Wih[gru];
    const float* __restrict__ bih = args.bih[gru];
    const float* __restrict__ bhh = args.bhh[gru];
    const _Float16* __restrict__ embf = args.emb[gru];
    const int* __restrict__ idx = args.idx[gru];

    const int u0 = ut * 32;        // block's hidden-unit base (32 units)
    const int mB = mt * 128;       // block's batch-row base (128 rows)

    __shared__ _Float16 Wl[3][32][KW];   // 124,416 B

    // ---- stage weights fp32 -> fp16 into LDS (once) ----
    for (int r = 0; r < 96; ++r) {            // r = gate*32 + uu
        const int g = r >> 5, uu = r & 31;
        const int row = g * H_SZ + u0 + uu;
        for (int k = threadIdx.x; k < KW; k += 256) {
            float v = 0.0f;
            if (k < H_SZ)                 v = Whh[row * H_SZ + k];
            else if (k < H_SZ + E_SZ)     v = Wih[row * E_SZ + (k - H_SZ)];
            Wl[g][uu][k] = (_Float16)v;
        }
    }
    __syncthreads();

    const int lane = threadIdx.x & 63;
    const int wave = threadIdx.x >> 6;   // 0..3
    const int lr   = lane & 15;          // fragment row
    const int kseg = lane >> 4;          // 0..3
    const int mw   = mB + wave * 32;     // wave's 32-row batch base

    // bias preload: this thread's two u columns (ut2 = 0,1)
    float bir[2], biz[2], binn[2], bhn[2];
    int ucol[2];
#pragma unroll
    for (int ut2 = 0; ut2 < 2; ++ut2) {
        ucol[ut2] = u0 + ut2 * 16 + lr;
        const int u = ucol[ut2];
        bir[ut2]  = bih[u]             + bhh[u];
        biz[ut2]  = bih[H_SZ + u]      + bhh[H_SZ + u];
        binn[ut2] = bih[2 * H_SZ + u];
        bhn[ut2]  = bhh[2 * H_SZ + u];
    }

    _Float16* hbuf0 = args.hA + (size_t)gru * B_SZ * H_SZ;
    _Float16* hbuf1 = args.hB + (size_t)gru * B_SZ * H_SZ;
    unsigned int* bar = args.bars + grp * 32;

    // h_prev at this thread's own output coordinates, carried in registers.
    float hreg[2][2][4] = {};   // [mt2][ut2][r]

#pragma unroll 1
    for (int step = 0; step < L_SZ; ++step) {
        const _Float16* __restrict__ hin = (step & 1) ? hbuf1 : hbuf0;
        _Float16* __restrict__ hout      = (step & 1) ? hbuf0 : hbuf1;
        const int lcol = L_SZ - 1 - step;

        f32x4 accr[2][2], accz[2][2], acchn[2][2], accin[2][2];
#pragma unroll
        for (int i = 0; i < 2; i++)
#pragma unroll
            for (int j = 0; j < 2; j++) {
                accr[i][j]  = (f32x4){0.f, 0.f, 0.f, 0.f};
                accz[i][j]  = (f32x4){0.f, 0.f, 0.f, 0.f};
                acchn[i][j] = (f32x4){0.f, 0.f, 0.f, 0.f};
                accin[i][j] = (f32x4){0.f, 0.f, 0.f, 0.f};
            }

        // ---- x-part first (emb only -- independent of h(step)) ----
        const int iv0 = idx[(mw + lr) * L_SZ + lcol];
        const int iv1 = idx[(mw + 16 + lr) * L_SZ + lcol];
#pragma unroll
        for (int xc = 0; xc < 4; ++xc) {
            const int e0 = xc * 32 + kseg * 8;
            f16x8 a0 = *(const f16x8*)(embf + (size_t)iv0 * KX + e0);
            f16x8 a1 = *(const f16x8*)(embf + (size_t)iv1 * KX + e0);
#pragma unroll
            for (int ut2 = 0; ut2 < 2; ++ut2) {
                f16x8 b0 = *(const f16x8*)&Wl[0][ut2 * 16 + lr][H_SZ + e0];
                f16x8 b1 = *(const f16x8*)&Wl[1][ut2 * 16 + lr][H_SZ + e0];
                f16x8 b2 = *(const f16x8*)&Wl[2][ut2 * 16 + lr][H_SZ + e0];
                accr[0][ut2]  = MFMA16(a0, b0, accr[0][ut2]);
                accr[1][ut2]  = MFMA16(a1, b0, accr[1][ut2]);
                accz[0][ut2]  = MFMA16(a0, b1, accz[0][ut2]);
                accz[1][ut2]  = MFMA16(a1, b1, accz[1][ut2]);
                accin[0][ut2] = MFMA16(a0, b2, accin[0][ut2]);
                accin[1][ut2] = MFMA16(a1, b2, accin[1][ut2]);
            }
        }

        // ---- wait for h(step): R9's proven LLC barrier ----
        if (step > 0) {
            if (threadIdx.x == 0) {
                const unsigned tgt = 16u * (unsigned)step;
                while (__hip_atomic_load(bar, __ATOMIC_RELAXED,
                                         __HIP_MEMORY_SCOPE_AGENT) < tgt)
                    __builtin_amdgcn_s_sleep(1);
            }
            __syncthreads();
        }

        // ---- h-part A-slab: full K = 512 in ONE asm batch.
        // 32 pipelined sc0 loads (bypass L1, read local L2 where the
        // same-XCD producers' stores live), single vmcnt(0). ----
        const _Float16* hrow0 = hin + (mw + lr) * H_SZ + kseg * 8;
        const _Float16* hrow1 = hin + (mw + 16 + lr) * H_SZ + kseg * 8;
        f16x8 a0h[16], a1h[16];
        asm volatile(
            "global_load_dwordx4 %0,  %32, off sc0\n\t"
            "global_load_dwordx4 %1,  %32, off offset:64 sc0\n\t"
            "global_load_dwordx4 %2,  %32, off offset:128 sc0\n\t"
            "global_load_dwordx4 %3,  %32, off offset:192 sc0\n\t"
            "global_load_dwordx4 %4,  %32, off offset:256 sc0\n\t"
            "global_load_dwordx4 %5,  %32, off offset:320 sc0\n\t"
            "global_load_dwordx4 %6,  %32, off offset:384 sc0\n\t"
            "global_load_dwordx4 %7,  %32, off offset:448 sc0\n\t"
            "global_load_dwordx4 %8,  %32, off offset:512 sc0\n\t"
            "global_load_dwordx4 %9,  %32, off offset:576 sc0\n\t"
            "global_load_dwordx4 %10, %32, off offset:640 sc0\n\t"
            "global_load_dwordx4 %11, %32, off offset:704 sc0\n\t"
            "global_load_dwordx4 %12, %32, off offset:768 sc0\n\t"
            "global_load_dwordx4 %13, %32, off offset:832 sc0\n\t"
            "global_load_dwordx4 %14, %32, off offset:896 sc0\n\t"
            "global_load_dwordx4 %15, %32, off offset:960 sc0\n\t"
            "global_load_dwordx4 %16, %33, off sc0\n\t"
            "global_load_dwordx4 %17, %33, off offset:64 sc0\n\t"
            "global_load_dwordx4 %18, %33, off offset:128 sc0\n\t"
            "global_load_dwordx4 %19, %33, off offset:192 sc0\n\t"
            "global_load_dwordx4 %20, %33, off offset:256 sc0\n\t"
            "global_load_dwordx4 %21, %33, off offset:320 sc0\n\t"
            "global_load_dwordx4 %22, %33, off offset:384 sc0\n\t"
            "global_load_dwordx4 %23, %33, off offset:448 sc0\n\t"
            "global_load_dwordx4 %24, %33, off offset:512 sc0\n\t"
            "global_load_dwordx4 %25, %33, off offset:576 sc0\n\t"
            "global_load_dwordx4 %26, %33, off offset:640 sc0\n\t"
            "global_load_dwordx4 %27, %33, off offset:704 sc0\n\t"
            "global_load_dwordx4 %28, %33, off offset:768 sc0\n\t"
            "global_load_dwordx4 %29, %33, off offset:832 sc0\n\t"
            "global_load_dwordx4 %30, %33, off offset:896 sc0\n\t"
            "global_load_dwordx4 %31, %33, off offset:960 sc0\n\t"
            "s_waitcnt vmcnt(0)"
            : "=&v"(a0h[0]),  "=&v"(a0h[1]),  "=&v"(a0h[2]),  "=&v"(a0h[3]),
              "=&v"(a0h[4]),  "=&v"(a0h[5]),  "=&v"(a0h[6]),  "=&v"(a0h[7]),
              "=&v"(a0h[8]),  "=&v"(a0h[9]),  "=&v"(a0h[10]), "=&v"(a0h[11]),
              "=&v"(a0h[12]), "=&v"(a0h[13]), "=&v"(a0h[14]), "=&v"(a0h[15]),
              "=&v"(a1h[0]),  "=&v"(a1h[1]),  "=&v"(a1h[2]),  "=&v"(a1h[3]),
              "=&v"(a1h[4]),  "=&v"(a1h[5]),  "=&v"(a1h[6]),  "=&v"(a1h[7]),
              "=&v"(a1h[8]),  "=&v"(a1h[9]),  "=&v"(a1h[10]), "=&v"(a1h[11]),
              "=&v"(a1h[12]), "=&v"(a1h[13]), "=&v"(a1h[14]), "=&v"(a1h[15])
            : "v"(hrow0), "v"(hrow1)
            : "memory");

        // ---- h-part MFMAs: 16 kc x 12 ----
#pragma unroll
        for (int kc = 0; kc < 16; ++kc) {
            const int k0 = kc * 32 + kseg * 8;
#pragma unroll
            for (int ut2 = 0; ut2 < 2; ++ut2) {
                f16x8 b0 = *(const f16x8*)&Wl[0][ut2 * 16 + lr][k0];
                f16x8 b1 = *(const f16x8*)&Wl[1][ut2 * 16 + lr][k0];
                f16x8 b2 = *(const f16x8*)&Wl[2][ut2 * 16 + lr][k0];
                accr[0][ut2]  = MFMA16(a0h[kc], b0, accr[0][ut2]);
                accr[1][ut2]  = MFMA16(a1h[kc], b0, accr[1][ut2]);
                accz[0][ut2]  = MFMA16(a0h[kc], b1, accz[0][ut2]);
                accz[1][ut2]  = MFMA16(a1h[kc], b1, accz[1][ut2]);
                acchn[0][ut2] = MFMA16(a0h[kc], b2, acchn[0][ut2]);
                acchn[1][ut2] = MFMA16(a1h[kc], b2, acchn[1][ut2]);
            }
        }

        // ---- epilogue: gates + state update; PLAIN stores -> local L2 ----
        // C/D layout: col = lane&15 (u), row = (lane>>4)*4 + reg (m)
#pragma unroll
        for (int mt2 = 0; mt2 < 2; ++mt2) {
#pragma unroll
            for (int ut2 = 0; ut2 < 2; ++ut2) {
#pragma unroll
                for (int r = 0; r < 4; ++r) {
                    const int m = mw + mt2 * 16 + kseg * 4 + r;
                    const float rg = fast_sigmoid(accr[mt2][ut2][r] + bir[ut2]);
                    const float zg = fast_sigmoid(accz[mt2][ut2][r] + biz[ut2]);
                    const float ng = fast_tanh(accin[mt2][ut2][r] + binn[ut2] +
                                               rg * (acchn[mt2][ut2][r] + bhn[ut2]));
                    float nh = (1.0f - zg) * ng + zg * hreg[mt2][ut2][r];
                    nh = (float)(_Float16)nh;   // bit-match the stored fp16
                    hreg[mt2][ut2][r] = nh;
                    hout[m * H_SZ + ucol[ut2]] = (_Float16)nh;
                }
            }
        }

        // ---- publish (RELAXED agent; stores drained to L2 by syncthreads) ----
        if (step + 1 < L_SZ) {
            __syncthreads();   // emits s_waitcnt vmcnt(0): stores visible in L2
            if (threadIdx.x == 0) {
                __hip_atomic_fetch_add(bar, 1u, __ATOMIC_RELAXED,
                                       __HIP_MEMORY_SCOPE_AGENT);
            }
        }
    }
    // final h (step 127, odd) in hA as dirty local-L2 lines; the dispatch-end
    // release writes them back so the scores kernel sees them.
}

// ---------------------------------------------------------------------------
// scores = hc @ hr^T (fp16 in, fp32 out), MFMA. Block 64x64, wave 32x32.
// ---------------------------------------------------------------------------
__global__ __launch_bounds__(256, 1) void scores_kernel(
    const _Float16* __restrict__ hc, const _Float16* __restrict__ hr,
    float* __restrict__ out)
{
    const int lane = threadIdx.x & 63;
    const int wave = threadIdx.x >> 6;
    const int lr   = lane & 15;
    const int kseg = lane >> 4;
    const int m0 = blockIdx.y * 64 + (wave >> 1) * 32;
    const int n0 = blockIdx.x * 64 + (wave & 1) * 32;

    f32x4 acc[2][2];
#pragma unroll
    for (int i = 0; i < 2; i++)
#pragma unroll
        for (int j = 0; j < 2; j++)
            acc[i][j] = (f32x4){0.f, 0.f, 0.f, 0.f};

#pragma unroll 2
    for (int kc = 0; kc < 16; kc++) {
        const int k0 = kc * 32 + kseg * 8;
        f16x8 a[2], b[2];
#pragma unroll
        for (int mt = 0; mt < 2; mt++)
            a[mt] = *(const f16x8*)(hc + (m0 + mt * 16 + lr) * H_SZ + k0);
#pragma unroll
        for (int nt = 0; nt < 2; nt++)
            b[nt] = *(const f16x8*)(hr + (n0 + nt * 16 + lr) * H_SZ + k0);
#pragma unroll
        for (int mt = 0; mt < 2; mt++)
#pragma unroll
            for (int nt = 0; nt < 2; nt++)
                acc[mt][nt] = MFMA16(a[mt], b[nt], acc[mt][nt]);
    }

#pragma unroll
    for (int mt = 0; mt < 2; mt++)
#pragma unroll
        for (int nt = 0; nt < 2; nt++)
#pragma unroll
            for (int r = 0; r < 4; r++) {
                const int m = m0 + mt * 16 + kseg * 4 + r;
                const int n = n0 + nt * 16 + lr;
                out[m * B_SZ + n] = acc[mt][nt][r];
            }
}

// In-place row softmax on [1024, 1024]; one block per row.
__global__ __launch_bounds__(256) void softmax_kernel(float* __restrict__ out)
{
    const int row = blockIdx.x;
    float* p = out + (size_t)row * B_SZ;
    const int t = threadIdx.x;
    const int wave = t >> 6;
    const int lane = t & 63;

    float4 v = ((const float4*)p)[t];
    float m = fmaxf(fmaxf(v.x, v.y), fmaxf(v.z, v.w));
#pragma unroll
    for (int off = 32; off >= 1; off >>= 1)
        m = fmaxf(m, __shfl_xor(m, off, 64));

    __shared__ float redm[4];
    if (lane == 0) redm[wave] = m;
    __syncthreads();
    m = fmaxf(fmaxf(redm[0], redm[1]), fmaxf(redm[2], redm[3]));

    const float e0 = __expf(v.x - m);
    const float e1 = __expf(v.y - m);
    const float e2 = __expf(v.z - m);
    const float e3 = __expf(v.w - m);
    float s = e0 + e1 + e2 + e3;
#pragma unroll
    for (int off = 32; off >= 1; off >>= 1)
        s += __shfl_xor(s, off, 64);

    __shared__ float reds[4];
    if (lane == 0) reds[wave] = s;
    __syncthreads();
    s = reds[0] + reds[1] + reds[2] + reds[3];

    const float inv = 1.0f / s;
    float4 o;
    o.x = e0 * inv; o.y = e1 * inv; o.z = e2 * inv; o.w = e3 * inv;
    ((float4*)p)[t] = o;
}

extern "C" void kernel_launch(void* const* d_in, const int* in_sizes, int n_in,
                              void* d_out, int out_size, void* d_ws, size_t ws_size,
                              hipStream_t stream)
{
    (void)in_sizes; (void)n_in; (void)out_size; (void)ws_size;

    const int*   contexts = (const int*)d_in[0];
    const int*   replies  = (const int*)d_in[1];
    const float* ctx_emb  = (const float*)d_in[2];
    const float* ctx_Wih  = (const float*)d_in[3];
    const float* ctx_Whh  = (const float*)d_in[4];
    const float* ctx_bih  = (const float*)d_in[5];
    const float* ctx_bhh  = (const float*)d_in[6];
    const float* rep_emb  = (const float*)d_in[7];
    const float* rep_Wih  = (const float*)d_in[8];
    const float* rep_Whh  = (const float*)d_in[9];
    const float* rep_bih  = (const float*)d_in[10];
    const float* rep_bhh  = (const float*)d_in[11];
    float* out = (float*)d_out;

    // ---- workspace layout (fp16 elements) ----
    const size_t EMB_ELEMS = (size_t)VOCAB * KX;          // 6,400,000
    const size_t H_ELEMS   = (size_t)B_SZ * H_SZ;         // 524,288

    _Float16* base   = (_Float16*)d_ws;
    _Float16* embf_c = base;
    _Float16* embf_r = embf_c + EMB_ELEMS;
    _Float16* hB     = embf_r + EMB_ELEMS;     // pong [2][B][H]
    _Float16* hA     = hB + 2 * H_ELEMS;       // ping [2][B][H]
    unsigned int* bars  = (unsigned int*)(hA + 2 * H_ELEMS);  // 16*32 uints
    unsigned int* claim = bars + 16 * 32;                     // 8 uints

    // zero h0 (both GRUs, ping), barrier counters, and claim counters.
    hipMemsetAsync(hA, 0,
                   2 * H_ELEMS * sizeof(_Float16) +
                   (16 * 32 + 8) * sizeof(unsigned int), stream);

    // embedding tables fp32 -> fp16 (padded to 128)
    {
        const int total_emb = 2 * (int)EMB_ELEMS;
        prep_emb_kernel<<<(total_emb + 255) / 256, 256, 0, stream>>>(
            embf_c, ctx_emb, embf_r, rep_emb);
    }

    // one persistent kernel for all 128 GRU steps (both GRUs)
    GruArgs a;
    a.Whh[0] = ctx_Whh; a.Whh[1] = rep_Whh;
    a.Wih[0] = ctx_Wih; a.Wih[1] = rep_Wih;
    a.bih[0] = ctx_bih; a.bih[1] = rep_bih;
    a.bhh[0] = ctx_bhh; a.bhh[1] = rep_bhh;
    a.emb[0] = embf_c;  a.emb[1] = embf_r;
    a.idx[0] = contexts; a.idx[1] = replies;
    a.hA = hA; a.hB = hB; a.bars = bars; a.claim = claim;
    gru_persistent<<<dim3(256), dim3(256), 0, stream>>>(a);

    // final states: gru0 (ctx) at hA, gru1 (rep) at hA + B*H
    scores_kernel<<<dim3(B_SZ / 64, B_SZ / 64), 256, 0, stream>>>(hA, hA + H_ELEMS, out);
    softmax_kernel<<<B_SZ, 256, 0, stream>>>(out);
}